// Round 2
// baseline (581.039 us; speedup 1.0000x reference)
//
#include <hip/hip_runtime.h>

// OSQP batched ADMM, B=256 N=128 M=192, 400 iters. Two-kernel design.
//
// Algebra (validated R1): M = P + sigma*I + rho*A^T A (SPD); W = M^-1 A^T;
// c = M^-1 q;  iterate: xt = W s - c ; w = A xt ; x = a*xt+(1-a)x ;
// v = a*w+(1-a)z + y/rho ; z = clip(v,l,u) ; y = rho*(v-z) ; s = rho*z - y.
//
// Kernel 1 (512 thr/block, 64KiB LDS): phases A (AtA), B (Gauss-Jordan
// inverse), C (W = Minv A^T, c = Minv q) -> d_ws.   [R1-proven code]
// Kernel 2 (1024 thr/block = 16 waves/CU, ~1.3KiB LDS): the 400-iter loop.
// W rows (2x12 fl) + A rows (3x8 fl) in VGPRs as float2 (v_pk_fma_f32),
// s/xt in LDS, DPP red16 reductions, 2 barriers/iter.

#define Nn 128
#define Mm 192
constexpr float RHO_    = 0.1f;
constexpr float RHOINV_ = 10.0f;
constexpr float SIGMA_  = 1e-6f;
constexpr float ALPHA_  = 1.6f;
constexpr int   NITERS_ = 400;

typedef float v2f __attribute__((ext_vector_type(2)));
typedef float v4f __attribute__((ext_vector_type(4)));

template<int CTRL>
__device__ __forceinline__ float dpp_add(float x) {
  int y = __builtin_amdgcn_update_dpp(0, __float_as_int(x), CTRL, 0xF, 0xF, false);
  return x + __int_as_float(y);
}
// sum across aligned 16-lane group (DPP row): row_ror 1,2,4,8
__device__ __forceinline__ float red16(float x) {
  x = dpp_add<0x121>(x); x = dpp_add<0x122>(x);
  x = dpp_add<0x124>(x); x = dpp_add<0x128>(x);
  return x;
}

//======================= Kernel 1: precompute W, c =================================
__global__ void __launch_bounds__(512, 2)
precompute_kernel(const float* __restrict__ Pg, const float* __restrict__ qg,
                  const float* __restrict__ Ag, float* __restrict__ wsW,
                  float* __restrict__ wsC)
{
  __shared__ float smem[16384];   // 64 KiB, aliased across phases
  const int t = threadIdx.x;
  const int b = blockIdx.x;
  const float* __restrict__ Pb = Pg + (size_t)b*Nn*Nn;
  const float* __restrict__ qb = qg + (size_t)b*Nn;
  const float* __restrict__ Ab = Ag + (size_t)b*Mm*Nn;

  //---- Phase A: S = P + sigma*I + rho * A^T A (S in LDS) ----
  {
    const int ar = t & 31;   // 32 row-groups of 4 rows
    const int bc = t >> 5;   // 16 col-groups of 8 cols
    float acc[4][8];
    #pragma unroll
    for (int a=0;a<4;a++)
      #pragma unroll
      for (int j=0;j<8;j++) acc[a][j]=0.f;

    for (int c=0;c<6;c++) {
      __syncthreads();
      { // stage A rows [32c,32c+32) x 128 into smem[0:4096]
        const float4* src = (const float4*)(Ab + c*32*Nn);
        float4* dst = (float4*)smem;
        dst[t]     = src[t];
        dst[t+512] = src[t+512];
      }
      __syncthreads();
      #pragma unroll 2
      for (int m=0;m<32;m++) {
        const float4 ra  = *(const float4*)&smem[m*Nn + 4*ar];
        const float4 cb0 = *(const float4*)&smem[m*Nn + 8*bc];
        const float4 cb1 = *(const float4*)&smem[m*Nn + 8*bc + 4];
        const float rv[4] = {ra.x, ra.y, ra.z, ra.w};
        const float cv[8] = {cb0.x,cb0.y,cb0.z,cb0.w,cb1.x,cb1.y,cb1.z,cb1.w};
        #pragma unroll
        for (int a=0;a<4;a++)
          #pragma unroll
          for (int j=0;j<8;j++) acc[a][j] += rv[a]*cv[j];
      }
    }
    __syncthreads();
    #pragma unroll
    for (int a=0;a<4;a++) {
      const int i = 4*ar + a;
      #pragma unroll
      for (int j=0;j<8;j++) {
        const int jj = 8*bc + j;
        float v = Pb[i*Nn + jj] + RHO_*acc[a][j];
        if (i == jj) v += SIGMA_;
        smem[i*Nn + jj] = v;
      }
    }
    __syncthreads();
  }

  //---- Phase B: S <- S^-1, in-place Gauss-Jordan (SPD, no pivot) ----
  {
    const int irow = t >> 2;   // 0..127
    const int qq   = t & 3;    // col quarter [32qq, 32qq+32)
    float rr[32];
    #pragma unroll
    for (int j=0;j<32;j++) rr[j] = smem[irow*Nn + 32*qq + j];
    __syncthreads();
    float* rowk = smem;        // [128]
    float* fcol = smem + Nn;   // [128]
    for (int k0=0;k0<4;k0++) {
      #pragma unroll            // full unroll: rr[kk] index must be static
      for (int kk=0;kk<32;kk++) {
        const int k = 32*k0 + kk;
        if (irow == k) {
          #pragma unroll
          for (int j=0;j<32;j++) rowk[32*qq+j] = rr[j];
        }
        if (qq == k0) fcol[irow] = rr[kk];
        __syncthreads();
        const float pinv = 1.0f / rowk[k];
        if (irow == k) {
          #pragma unroll
          for (int j=0;j<32;j++) rr[j] *= pinv;
          if (qq == k0) rr[kk] = pinv;
        } else {
          const float gfac = fcol[irow] * pinv;
          #pragma unroll
          for (int j=0;j<32;j++) rr[j] -= gfac * rowk[32*qq+j];
          if (qq == k0) rr[kk] = -gfac;
        }
        __syncthreads();
      }
    }
    #pragma unroll
    for (int j=0;j<32;j++) smem[irow*Nn + 32*qq + j] = rr[j];  // write Minv back
  }
  __syncthreads();

  //---- Phase C: W = Minv A^T (rows in regs), c = Minv q; store to ws ----
  const int rg = t >> 4, cg = t & 15;

  float g[4][12];                        // W[4rg+a][12cg+ii]
  #pragma unroll
  for (int a=0;a<4;a++)
    #pragma unroll
    for (int ii=0;ii<12;ii++) g[a][ii]=0.f;
  for (int k4=0;k4<32;k4++) {
    float4 mv0 = *(const float4*)&smem[(4*rg+0)*Nn + 4*k4];
    float4 mv1 = *(const float4*)&smem[(4*rg+1)*Nn + 4*k4];
    float4 mv2 = *(const float4*)&smem[(4*rg+2)*Nn + 4*k4];
    float4 mv3 = *(const float4*)&smem[(4*rg+3)*Nn + 4*k4];
    #pragma unroll
    for (int ii=0;ii<12;ii++) {
      const int j = 12*cg + ii;
      const float4 av = *(const float4*)&Ab[j*Nn + 4*k4];
      g[0][ii] += mv0.x*av.x + mv0.y*av.y + mv0.z*av.z + mv0.w*av.w;
      g[1][ii] += mv1.x*av.x + mv1.y*av.y + mv1.z*av.z + mv1.w*av.w;
      g[2][ii] += mv2.x*av.x + mv2.y*av.y + mv2.z*av.z + mv2.w*av.w;
      g[3][ii] += mv3.x*av.x + mv3.y*av.y + mv3.z*av.z + mv3.w*av.w;
    }
  }

  float c_reg = 0.f;                     // c[r] = Minv[r,:].q
  {
    const int r = 4*rg + (cg & 3);
    for (int k4=0;k4<32;k4++) {
      const float4 mvv = *(const float4*)&smem[r*Nn + 4*k4];
      const float4 qv  = *(const float4*)&qb[4*k4];
      c_reg += mvv.x*qv.x + mvv.y*qv.y + mvv.z*qv.z + mvv.w*qv.w;
    }
  }

  float* wrow = wsW + (size_t)b*Nn*Mm;
  #pragma unroll
  for (int a=0;a<4;a++) {
    float4* dst = (float4*)(wrow + (4*rg+a)*Mm + 12*cg);
    dst[0] = make_float4(g[a][0], g[a][1], g[a][2],  g[a][3]);
    dst[1] = make_float4(g[a][4], g[a][5], g[a][6],  g[a][7]);
    dst[2] = make_float4(g[a][8], g[a][9], g[a][10], g[a][11]);
  }
  if (cg < 4) wsC[(size_t)b*Nn + 4*rg + cg] = c_reg;
}

//======================= Kernel 2: 400-iteration ADMM loop =========================
// 1024 threads = 16 waves/CU. Both stages use (rg = t>>4 in 0..63, cg = t&15).
// Stage1: rows {2rg, 2rg+1}, s-chunk [12cg, 12cg+12).  red16 x2.
// Stage2: rows {3rg..3rg+2}, xt-chunk [8cg, 8cg+8).    red16 x3.
// xt padded +4 floats per 32 -> stage2 b128 reads are 2-way (free).
__global__ void __launch_bounds__(1024, 4)
loop_kernel(const float* __restrict__ Ag, const float* __restrict__ lg,
            const float* __restrict__ ug, const float* __restrict__ wsW,
            const float* __restrict__ wsC, float* __restrict__ outg)
{
  __shared__ float sbuf[Mm];     // s[192]
  __shared__ float xtb[144];     // xt padded: idx r + 4*(r>>5)
  const int t = threadIdx.x;
  const int b = blockIdx.x;
  const int rg = t >> 4, cg = t & 15;

  // ---- load W rows (2 x 12 floats) as v2f ----
  v2f g2[2][6];
  #pragma unroll
  for (int a=0;a<2;a++) {
    const v4f* wp = (const v4f*)(wsW + (size_t)b*Nn*Mm + (2*rg+a)*Mm + 12*cg);
    const v4f w0 = wp[0], w1 = wp[1], w2 = wp[2];
    g2[a][0] = (v2f){w0.x,w0.y}; g2[a][1] = (v2f){w0.z,w0.w};
    g2[a][2] = (v2f){w1.x,w1.y}; g2[a][3] = (v2f){w1.z,w1.w};
    g2[a][4] = (v2f){w2.x,w2.y}; g2[a][5] = (v2f){w2.z,w2.w};
  }
  // ---- load A rows (3 x 8 floats) as v2f ----
  v2f af2[3][4];
  #pragma unroll
  for (int a=0;a<3;a++) {
    const v4f* ap = (const v4f*)(Ag + (size_t)b*Mm*Nn + (3*rg+a)*Nn + 8*cg);
    const v4f a0 = ap[0], a1 = ap[1];
    af2[a][0] = (v2f){a0.x,a0.y}; af2[a][1] = (v2f){a0.z,a0.w};
    af2[a][2] = (v2f){a1.x,a1.y}; af2[a][3] = (v2f){a1.z,a1.w};
  }

  const int prow = 2*rg + cg;            // stage1 producer row (cg<2)
  const int pm   = 3*rg + cg;            // stage2 producer row (cg<3)
  float c_reg = 0.f, lreg = 0.f, ureg = 0.f;
  if (cg < 2) c_reg = wsC[(size_t)b*Nn + prow];
  if (cg < 3) { lreg = lg[(size_t)b*Mm + pm]; ureg = ug[(size_t)b*Mm + pm]; }

  if (t < Mm) sbuf[t] = 0.f;             // s0 = 0
  __syncthreads();

  float xreg = 0.f, zreg = 0.f, yreg = 0.f;
  const v4f* s4 = (const v4f*)(sbuf + 12*cg);               // 16B-aligned
  const v4f* x4 = (const v4f*)(xtb + 8*cg + 4*(cg>>2));     // padded, 16B-aligned

  #pragma unroll 1
  for (int it=0; it<NITERS_; it++) {
    // ---- stage 1: xt = W s - c ; x update ----
    const v4f sA = s4[0], sB = s4[1], sC = s4[2];
    v2f sv0 = (v2f){sA.x,sA.y}, sv1 = (v2f){sA.z,sA.w};
    v2f sv2 = (v2f){sB.x,sB.y}, sv3 = (v2f){sB.z,sB.w};
    v2f sv4 = (v2f){sC.x,sC.y}, sv5 = (v2f){sC.z,sC.w};
    v2f acc0 = g2[0][0]*sv0; v2f acc1 = g2[1][0]*sv0;
    acc0 += g2[0][1]*sv1;    acc1 += g2[1][1]*sv1;
    acc0 += g2[0][2]*sv2;    acc1 += g2[1][2]*sv2;
    acc0 += g2[0][3]*sv3;    acc1 += g2[1][3]*sv3;
    acc0 += g2[0][4]*sv4;    acc1 += g2[1][4]*sv4;
    acc0 += g2[0][5]*sv5;    acc1 += g2[1][5]*sv5;
    float v0 = acc0.x + acc0.y;
    float v1 = acc1.x + acc1.y;
    v0 = red16(v0); v1 = red16(v1);
    if (cg < 2) {
      const float xtv = ((cg==0) ? v0 : v1) - c_reg;
      xtb[prow + 4*(prow>>5)] = xtv;
      xreg = ALPHA_*xtv + (1.f-ALPHA_)*xreg;
    }
    __syncthreads();
    // ---- stage 2: w = A xt ; z,y,s update ----
    const v4f xA = x4[0], xB = x4[1];
    v2f xv0 = (v2f){xA.x,xA.y}, xv1 = (v2f){xA.z,xA.w};
    v2f xv2 = (v2f){xB.x,xB.y}, xv3 = (v2f){xB.z,xB.w};
    v2f b0 = af2[0][0]*xv0; v2f b1 = af2[1][0]*xv0; v2f b2 = af2[2][0]*xv0;
    b0 += af2[0][1]*xv1;    b1 += af2[1][1]*xv1;    b2 += af2[2][1]*xv1;
    b0 += af2[0][2]*xv2;    b1 += af2[1][2]*xv2;    b2 += af2[2][2]*xv2;
    b0 += af2[0][3]*xv3;    b1 += af2[1][3]*xv3;    b2 += af2[2][3]*xv3;
    float w0 = b0.x + b0.y;
    float w1 = b1.x + b1.y;
    float w2 = b2.x + b2.y;
    w0 = red16(w0); w1 = red16(w1); w2 = red16(w2);
    if (cg < 3) {
      const float w  = (cg==0)?w0 : (cg==1)?w1 : w2;
      const float zc = ALPHA_*w + (1.f-ALPHA_)*zreg;
      const float vv = zc + yreg*RHOINV_;
      const float zn = fminf(fmaxf(vv, lreg), ureg);
      yreg = RHO_*(vv - zn);
      zreg = zn;
      sbuf[pm] = RHO_*zreg - yreg;
    }
    __syncthreads();
  }

  if (cg < 2) outg[(size_t)b*Nn + prow] = xreg;
}

extern "C" void kernel_launch(void* const* d_in, const int* in_sizes, int n_in,
                              void* d_out, int out_size, void* d_ws, size_t ws_size,
                              hipStream_t stream) {
  const float* P = (const float*)d_in[0];
  const float* q = (const float*)d_in[1];
  const float* A = (const float*)d_in[2];
  const float* l = (const float*)d_in[3];
  const float* u = (const float*)d_in[4];
  (void)in_sizes; (void)n_in; (void)out_size; (void)ws_size;
  float* wsW = (float*)d_ws;                       // 256*128*192 floats = 25.2 MB
  float* wsC = wsW + (size_t)256*Nn*Mm;            // 256*128 floats
  precompute_kernel<<<256, 512, 0, stream>>>(P, q, A, wsW, wsC);
  loop_kernel<<<256, 1024, 0, stream>>>(A, l, u, wsW, wsC, (float*)d_out);
}

// Round 3
// 451.712 us; speedup vs baseline: 1.2863x; 1.2863x over previous
//
#include <hip/hip_runtime.h>

// OSQP batched ADMM, B=256 N=128 M=192, 400 iters.
// R3: constraint-space loop. Algebra (R1/R2-validated base):
//   M = P + sI + rho*AtA (SPD);  Wt = A*Minv (192x128);  c = Minv q
//   V = A Minv At = A * Wt^T-ish:  V[i][j] = dot(A_i, Wt_j)   (192x192)
//   d[i] = dot(A_i, c)
//   iterate (s_0=0): t = V s - d ; zc = a*t+(1-a)z ; v = zc + y/rho ;
//     z = clip(v,l,u) ; y = rho*(v-z) ; Sacc = (1-a)Sacc + a*s ; s = rho*z - y
//   epilogue: x = Wt^T Sacc - c   (cw_400 = 1-(-0.6)^400 = 1 exactly in fp32)
// Kernel 1: AtA -> GJ inverse (1 barrier/step, DPP pivot-col, padded rowk,
//           rcp+NR) -> Wt (LDS-broadcast Minv) + c -> d_ws.
// Kernel 2: prologue computes V rows into VGPRs (LDS-tiled), then 400 iters
//           with ONE barrier each; epilogue x.

#define Nn 128
#define Mm 192
constexpr float RHO_    = 0.1f;
constexpr float RHOINV_ = 10.0f;
constexpr float SIGMA_  = 1e-6f;
constexpr float ALPHA_  = 1.6f;
constexpr int   NITERS_ = 400;

typedef float v2f __attribute__((ext_vector_type(2)));
typedef float v4f __attribute__((ext_vector_type(4)));

template<int CTRL>
__device__ __forceinline__ float dpp_add(float x) {
  int y = __builtin_amdgcn_update_dpp(0, __float_as_int(x), CTRL, 0xF, 0xF, false);
  return x + __int_as_float(y);
}
// sum across aligned 16-lane group: row_ror 1,2,4,8
__device__ __forceinline__ float red16(float x) {
  x = dpp_add<0x121>(x); x = dpp_add<0x122>(x);
  x = dpp_add<0x124>(x); x = dpp_add<0x128>(x);
  return x;
}

//======================= Kernel 1: precompute Wt, c ================================
// Phase B GJ block: K0 = column-quarter index (static for DPP ctrl + qq mask).
// rowk double-buffered (parity = kk&1, static under unroll), stride 36 floats
// (16B-aligned, conflict-free across qq). One barrier per step.
template<int K0>
__device__ __forceinline__ void gj_block(float rr[32], float* __restrict__ buf0,
                                         float* __restrict__ buf1,
                                         const int irow, const int qq) {
  const bool qsel = (qq == K0);
  #pragma unroll
  for (int kk = 0; kk < 32; kk++) {
    const int k = 32*K0 + kk;
    float* wb = ((kk & 1) == 0) ? buf0 : buf1;
    if (irow == k) {            // 4 lanes store the (unnormalized) pivot row
      #pragma unroll
      for (int j4 = 0; j4 < 8; j4++)
        *(float4*)&wb[36*qq + 4*j4] = *(const float4*)&rr[4*j4];
    }
    __syncthreads();
    const float akk  = wb[36*K0 + kk];                 // broadcast read
    float pinv = __builtin_amdgcn_rcpf(akk);
    pinv = pinv + pinv*(1.0f - akk*pinv);              // 1 Newton step
    // pivot-column element of THIS row: rr[kk] lives in the qq==K0 lane of the quad
    constexpr int QP = K0 | (K0<<2) | (K0<<4) | (K0<<6);
    const int fi = __builtin_amdgcn_update_dpp(__float_as_int(rr[kk]),
                      __float_as_int(rr[kk]), QP, 0xF, 0xF, false);
    const float f = __int_as_float(fi);
    const bool piv = (irow == k);
    float gfac = f * pinv;
    gfac = piv ? (1.0f - pinv) : gfac;                 // uniform rank-1 update
    float rk[32];
    #pragma unroll
    for (int j4 = 0; j4 < 8; j4++)
      *(float4*)&rk[4*j4] = *(const float4*)&wb[36*qq + 4*j4];
    #pragma unroll
    for (int j = 0; j < 32; j++) rr[j] -= gfac * rk[j];
    const float pivfix = piv ? pinv : -gfac;
    if (qsel) rr[kk] = pivfix;                         // in-place inverse column
  }
}

__global__ void __launch_bounds__(512, 2)
precompute_kernel(const float* __restrict__ Pg, const float* __restrict__ qg,
                  const float* __restrict__ Ag, float* __restrict__ wsWt,
                  float* __restrict__ wsC)
{
  __shared__ float smem[16384];   // 64 KiB, aliased across phases
  const int t = threadIdx.x;
  const int b = blockIdx.x;
  const float* __restrict__ Pb = Pg + (size_t)b*Nn*Nn;
  const float* __restrict__ qb = qg + (size_t)b*Nn;
  const float* __restrict__ Ab = Ag + (size_t)b*Mm*Nn;

  //---- Phase A: S = P + sigma*I + rho * A^T A (S in LDS) ---- [R1-proven]
  {
    const int ar = t & 31;
    const int bc = t >> 5;
    float acc[4][8];
    #pragma unroll
    for (int a=0;a<4;a++)
      #pragma unroll
      for (int j=0;j<8;j++) acc[a][j]=0.f;

    for (int c=0;c<6;c++) {
      __syncthreads();
      {
        const float4* src = (const float4*)(Ab + c*32*Nn);
        float4* dst = (float4*)smem;
        dst[t]     = src[t];
        dst[t+512] = src[t+512];
      }
      __syncthreads();
      #pragma unroll 2
      for (int m=0;m<32;m++) {
        const float4 ra  = *(const float4*)&smem[m*Nn + 4*ar];
        const float4 cb0 = *(const float4*)&smem[m*Nn + 8*bc];
        const float4 cb1 = *(const float4*)&smem[m*Nn + 8*bc + 4];
        const float rv[4] = {ra.x, ra.y, ra.z, ra.w};
        const float cv[8] = {cb0.x,cb0.y,cb0.z,cb0.w,cb1.x,cb1.y,cb1.z,cb1.w};
        #pragma unroll
        for (int a=0;a<4;a++)
          #pragma unroll
          for (int j=0;j<8;j++) acc[a][j] += rv[a]*cv[j];
      }
    }
    __syncthreads();
    #pragma unroll
    for (int a=0;a<4;a++) {
      const int i = 4*ar + a;
      #pragma unroll
      for (int j=0;j<8;j++) {
        const int jj = 8*bc + j;
        float v = Pb[i*Nn + jj] + RHO_*acc[a][j];
        if (i == jj) v += SIGMA_;
        smem[i*Nn + jj] = v;
      }
    }
    __syncthreads();
  }

  //---- Phase B: S <- S^-1, Gauss-Jordan, rows in regs, 1 barrier/step ----
  {
    const int irow = t >> 2;
    const int qq   = t & 3;
    float rr[32];
    #pragma unroll
    for (int j=0;j<32;j++) rr[j] = smem[irow*Nn + 32*qq + j];
    __syncthreads();                  // all rr loaded before rowk bufs alias smem
    float* buf0 = smem;               // [144]
    float* buf1 = smem + 144;         // [144]
    gj_block<0>(rr, buf0, buf1, irow, qq);
    gj_block<1>(rr, buf0, buf1, irow, qq);
    gj_block<2>(rr, buf0, buf1, irow, qq);
    gj_block<3>(rr, buf0, buf1, irow, qq);
    __syncthreads();                  // step-127 reads done before overwrite
    #pragma unroll
    for (int j=0;j<32;j++) smem[irow*Nn + 32*qq + j] = rr[j];  // Minv
  }
  __syncthreads();

  //---- Phase C: Wt = A * Minv -> wsWt; c = Minv q -> wsC ----
  // jr = t&63 (A-row lane), kc = t>>6 (uniform per wave -> Minv LDS broadcast)
  {
    const int jr = t & 63, kc = t >> 6;
    v2f acc[3][8];
    #pragma unroll
    for (int a=0;a<3;a++)
      #pragma unroll
      for (int p=0;p<8;p++) acc[a][p] = (v2f){0.f,0.f};

    for (int mi=0; mi<32; mi++) {
      const v4f a0 = *(const v4f*)&Ab[(jr      )*Nn + 4*mi];
      const v4f a1 = *(const v4f*)&Ab[(jr +  64)*Nn + 4*mi];
      const v4f a2 = *(const v4f*)&Ab[(jr + 128)*Nn + 4*mi];
      const float am[3][4] = {{a0.x,a0.y,a0.z,a0.w},
                              {a1.x,a1.y,a1.z,a1.w},
                              {a2.x,a2.y,a2.z,a2.w}};
      #pragma unroll
      for (int q=0;q<4;q++) {
        const int m = 4*mi + q;
        const v4f w0 = *(const v4f*)&smem[m*Nn + 16*kc +  0];
        const v4f w1 = *(const v4f*)&smem[m*Nn + 16*kc +  4];
        const v4f w2 = *(const v4f*)&smem[m*Nn + 16*kc +  8];
        const v4f w3 = *(const v4f*)&smem[m*Nn + 16*kc + 12];
        const v2f wp[8] = {(v2f){w0.x,w0.y},(v2f){w0.z,w0.w},
                           (v2f){w1.x,w1.y},(v2f){w1.z,w1.w},
                           (v2f){w2.x,w2.y},(v2f){w2.z,w2.w},
                           (v2f){w3.x,w3.y},(v2f){w3.z,w3.w}};
        #pragma unroll
        for (int a=0;a<3;a++) {
          const v2f amv = (v2f){am[a][q], am[a][q]};
          #pragma unroll
          for (int p=0;p<8;p++) acc[a][p] += amv * wp[p];
        }
      }
    }
    float* wb = wsWt + (size_t)b*Mm*Nn;
    #pragma unroll
    for (int a=0;a<3;a++) {
      const int j = jr + 64*a;
      #pragma unroll
      for (int x=0;x<4;x++) {
        *(float4*)&wb[j*Nn + 16*kc + 4*x] =
          make_float4(acc[a][2*x].x, acc[a][2*x].y, acc[a][2*x+1].x, acc[a][2*x+1].y);
      }
    }
  }
  // c[r] = sum_k Minv[k][r] q[k]  (Minv symmetric; lane-consecutive reads)
  if (t < Nn) {
    float cc = 0.f;
    #pragma unroll 4
    for (int k=0;k<Nn;k++) cc += smem[k*Nn + t] * qb[k];
    wsC[(size_t)b*Nn + t] = cc;
  }
}

//======================= Kernel 2: V-space ADMM loop ===============================
// 1024 threads. ig = t>>4 (0..63), cg = t&15.
// Thread owns V rows {ig, ig+64, ig+128} x cols {cg+16m : m<12}.
// s stored transposed: sT[j&15][j>>4] at (j&15)*12 + (j>>4) -> contiguous reads.
// Producer lane (cg<3) owns constraint row pm = 64*cg + ig.
#define ABASE 0
#define WBASE 6912
__global__ void __launch_bounds__(1024, 4)
loop_kernel(const float* __restrict__ Ag, const float* __restrict__ lg,
            const float* __restrict__ ug, const float* __restrict__ wsWt,
            const float* __restrict__ wsC, float* __restrict__ outg)
{
  __shared__ float smem[13824];   // 54 KiB: A-tile[192][36] + Wt-tile[192][36]
  const int t = threadIdx.x, b = blockIdx.x;
  const int ig = t >> 4, cg = t & 15;
  const float* __restrict__ Ab = Ag   + (size_t)b*Mm*Nn;
  const float* __restrict__ Wb = wsWt + (size_t)b*Mm*Nn;
  const float* __restrict__ cb = wsC  + (size_t)b*Nn;

  const int  pm  = 64*cg + ig;          // producer row (cg<3)
  const bool isp = (cg < 3);

  // ---- d = A_pm . c ; bounds (producers) ----
  float dreg = 0.f, lreg = 0.f, ureg = 0.f;
  if (isp) {
    lreg = lg[(size_t)b*Mm + pm];
    ureg = ug[(size_t)b*Mm + pm];
    const float4* ar = (const float4*)(Ab + pm*Nn);
    const float4* cr = (const float4*)cb;
    #pragma unroll 4
    for (int k4=0;k4<32;k4++) {
      const float4 av = ar[k4], cv = cr[k4];
      dreg += av.x*cv.x + av.y*cv.y + av.z*cv.z + av.w*cv.w;
    }
  }

  // ---- prologue: V rows into regs.  V[i][cg+16jj] = dot(A_i, Wt_{cg+16jj}) ----
  v2f accv[3][12];                       // v2f over m-parity
  #pragma unroll
  for (int a=0;a<3;a++)
    #pragma unroll
    for (int jj=0;jj<12;jj++) accv[a][jj] = (v2f){0.f,0.f};

  for (int kc=0; kc<4; kc++) {
    __syncthreads();
    { // stage A[0:192][32kc:+32] and Wt[0:192][32kc:+32], padded stride 36
      int x = t;
      {
        const int row = x>>3, c4 = x&7;
        *(float4*)&smem[ABASE + 36*row + 4*c4] = *(const float4*)&Ab[row*Nn + 32*kc + 4*c4];
        *(float4*)&smem[WBASE + 36*row + 4*c4] = *(const float4*)&Wb[row*Nn + 32*kc + 4*c4];
      }
      if (t < 512) {
        x = t + 1024;
        const int row = x>>3, c4 = x&7;
        *(float4*)&smem[ABASE + 36*row + 4*c4] = *(const float4*)&Ab[row*Nn + 32*kc + 4*c4];
        *(float4*)&smem[WBASE + 36*row + 4*c4] = *(const float4*)&Wb[row*Nn + 32*kc + 4*c4];
      }
    }
    __syncthreads();
    #pragma unroll
    for (int m4=0; m4<8; m4++) {
      const v4f a0 = *(const v4f*)&smem[ABASE + 36*(ig      ) + 4*m4];
      const v4f a1 = *(const v4f*)&smem[ABASE + 36*(ig +  64) + 4*m4];
      const v4f a2 = *(const v4f*)&smem[ABASE + 36*(ig + 128) + 4*m4];
      #pragma unroll
      for (int jj=0; jj<12; jj++) {
        const v4f w = *(const v4f*)&smem[WBASE + 36*(cg + 16*jj) + 4*m4];
        const v2f wlo = (v2f){w.x,w.y}, whi = (v2f){w.z,w.w};
        accv[0][jj] += (v2f){a0.x,a0.y}*wlo + (v2f){a0.z,a0.w}*whi;
        accv[1][jj] += (v2f){a1.x,a1.y}*wlo + (v2f){a1.z,a1.w}*whi;
        accv[2][jj] += (v2f){a2.x,a2.y}*wlo + (v2f){a2.z,a2.w}*whi;
      }
    }
  }
  // pack: Vp[a][jp] = {V[i][cg+16*(2jp)], V[i][cg+16*(2jp+1)]}
  v2f Vp[3][6];
  #pragma unroll
  for (int a=0;a<3;a++)
    #pragma unroll
    for (int jp=0;jp<6;jp++)
      Vp[a][jp] = (v2f){accv[a][2*jp].x + accv[a][2*jp].y,
                        accv[a][2*jp+1].x + accv[a][2*jp+1].y};

  __syncthreads();                       // tile reads done; alias s buffers
  float* sT0  = smem;                    // [192]
  float* sT1  = smem + 192;              // [192]
  float* sacc = smem + 384;              // [192]
  if (t < Mm) sT0[t] = 0.f;              // s_0 = 0
  __syncthreads();

  const int woff = (pm & 15)*12 + (pm >> 4);   // producer write slot
  float sreg = 0.f, zreg = 0.f, yreg = 0.f, Sacc = 0.f;

#define ITER(RD, WR)                                                           \
  {                                                                            \
    const v4f sA = *(const v4f*)((RD) + 12*cg);                                \
    const v4f sB = *(const v4f*)((RD) + 12*cg + 4);                            \
    const v4f sC = *(const v4f*)((RD) + 12*cg + 8);                            \
    const v2f s0 = (v2f){sA.x,sA.y}, s1 = (v2f){sA.z,sA.w};                    \
    const v2f s2 = (v2f){sB.x,sB.y}, s3 = (v2f){sB.z,sB.w};                    \
    const v2f s4 = (v2f){sC.x,sC.y}, s5 = (v2f){sC.z,sC.w};                    \
    v2f t0 = Vp[0][0]*s0; v2f t1 = Vp[1][0]*s0; v2f t2 = Vp[2][0]*s0;          \
    t0 += Vp[0][1]*s1;    t1 += Vp[1][1]*s1;    t2 += Vp[2][1]*s1;             \
    t0 += Vp[0][2]*s2;    t1 += Vp[1][2]*s2;    t2 += Vp[2][2]*s2;             \
    t0 += Vp[0][3]*s3;    t1 += Vp[1][3]*s3;    t2 += Vp[2][3]*s3;             \
    t0 += Vp[0][4]*s4;    t1 += Vp[1][4]*s4;    t2 += Vp[2][4]*s4;             \
    t0 += Vp[0][5]*s5;    t1 += Vp[1][5]*s5;    t2 += Vp[2][5]*s5;             \
    float r0 = t0.x + t0.y, r1 = t1.x + t1.y, r2 = t2.x + t2.y;                \
    r0 = red16(r0); r1 = red16(r1); r2 = red16(r2);                            \
    if (isp) {                                                                 \
      const float w  = ((cg==0) ? r0 : (cg==1) ? r1 : r2) - dreg;              \
      const float zc = ALPHA_*w + (1.f-ALPHA_)*zreg;                           \
      const float vv = zc + yreg*RHOINV_;                                      \
      const float zn = fminf(fmaxf(vv, lreg), ureg);                           \
      const float yn = RHO_*(vv - zn);                                         \
      Sacc = (1.f-ALPHA_)*Sacc + ALPHA_*sreg;                                  \
      sreg = RHO_*zn - yn;                                                     \
      zreg = zn; yreg = yn;                                                    \
      (WR)[woff] = sreg;                                                       \
    }                                                                          \
    __syncthreads();                                                           \
  }

  #pragma unroll 1
  for (int it2 = 0; it2 < NITERS_/2; it2++) {
    ITER(sT0, sT1)
    ITER(sT1, sT0)
  }
#undef ITER

  // ---- epilogue: x = Wt^T Sacc - c ----
  if (isp) sacc[pm] = Sacc;
  __syncthreads();
  if (t < Nn) {
    float acc = -cb[t];
    #pragma unroll 4
    for (int j=0;j<Mm;j++) acc += Wb[j*Nn + t] * sacc[j];
    outg[(size_t)b*Nn + t] = acc;
  }
}

extern "C" void kernel_launch(void* const* d_in, const int* in_sizes, int n_in,
                              void* d_out, int out_size, void* d_ws, size_t ws_size,
                              hipStream_t stream) {
  const float* P = (const float*)d_in[0];
  const float* q = (const float*)d_in[1];
  const float* A = (const float*)d_in[2];
  const float* l = (const float*)d_in[3];
  const float* u = (const float*)d_in[4];
  (void)in_sizes; (void)n_in; (void)out_size; (void)ws_size;
  float* wsWt = (float*)d_ws;                      // 256*192*128 floats = 25.2 MB
  float* wsC  = wsWt + (size_t)256*Mm*Nn;          // 256*128 floats
  precompute_kernel<<<256, 512, 0, stream>>>(P, q, A, wsWt, wsC);
  loop_kernel<<<256, 1024, 0, stream>>>(A, l, u, wsWt, wsC, (float*)d_out);
}